// Round 11
// baseline (718.869 us; speedup 1.0000x reference)
//
#include <hip/hip_runtime.h>
#include <hip/hip_fp16.h>
#include <hip/hip_cooperative_groups.h>
#include <math.h>

namespace cg = cooperative_groups;

#define BB 4
#define NN 2304
#define CC 256
#define HS 48
#define HID 1024
#define BNROWS (BB * NN)                 // 9216
#define ATTN_SCALE 0.17677669529663687f  // 32^-0.5
#define NWAVES 2048                      // 256 blocks x 8 waves

typedef _Float16 f16;
typedef __attribute__((ext_vector_type(2))) _Float16 h2;
typedef __attribute__((ext_vector_type(8))) _Float16 h8;
typedef __attribute__((ext_vector_type(4))) float f4;

#define GLLS16(g, l)                                                        \
    __builtin_amdgcn_global_load_lds(                                       \
        (const __attribute__((address_space(1))) unsigned int*)(g),         \
        (__attribute__((address_space(3))) unsigned int*)(l), 16, 0, 0)
#define WAIT_VM0()   asm volatile("s_waitcnt vmcnt(0)" ::: "memory")
#define WAIT_LGKM0() asm volatile("s_waitcnt lgkmcnt(0)" ::: "memory")

__device__ __constant__ int ATT_DY[29] = {
    -3, -2, -2, -2, -2, -2, -1, -1, -1, -1, -1, 0, 0, 0, 0,
    0, 0, 0, 1, 1, 1, 1, 1, 2, 2, 2, 2, 2, 3};
__device__ __constant__ int ATT_DX[29] = {
    0, -2, -1, 0, 1, 2, -2, -1, 0, 1, 2, -3, -2, -1, 0,
    1, 2, 3, -2, -1, 0, 1, 2, -2, -1, 0, 1, 2, 0};

static __device__ __forceinline__ float wave_sum64(float v) {
    v += __shfl_xor(v, 32, 64);
    v += __shfl_xor(v, 16, 64);
    v += __shfl_xor(v, 8, 64);
    v += __shfl_xor(v, 4, 64);
    v += __shfl_xor(v, 2, 64);
    v += __shfl_xor(v, 1, 64);
    return v;
}

// ---------------- wave-autonomous GEMM phase (TM=32, r10-proven) ------------
// Wave-private LDS slot (A 32x32 + B 64x32 f16 = 6 KB), global_load_lds
// staging with cross-iteration prefetch; no intra-block barriers.
// LDS chunk swizzle: (row r, k-chunk q) -> slot (q+(r>>1))&3 [2-way = free].
template <bool GELU, int RESID, bool OUTF32, bool QKV>
static __device__ void gemm_phase(
    f16* slot, int gw,
    const f16* __restrict__ Aq, const f16* __restrict__ Akv,
    const f16* __restrict__ Bt, const float* __restrict__ bias,
    const void* __restrict__ resid, void* __restrict__ out1,
    void* __restrict__ outkv, int Mtiles, int Ntiles, int N, int K)
{
    const int lane = threadIdx.x & 63;
    const int ln15 = lane & 15, quad = lane >> 4;
    const int jr = lane >> 2, js = lane & 3;
    f16* Al = slot;
    f16* Bl = slot + 1024;
    const int T = Mtiles * Ntiles;

    for (int t = gw; t < T; t += NWAVES) {
        const int n0 = (t % Ntiles) * 64;
        const int m0 = (t / Ntiles) * 32;
        const f16* Ap = QKV ? (n0 < 256 ? Aq : Akv) : Aq;

        size_t ga[2], gb[4];
#pragma unroll
        for (int i = 0; i < 2; ++i) {
            const int r = i * 16 + jr;
            const int q = (js - (r >> 1)) & 3;
            ga[i] = (size_t)(m0 + r) * K + q * 8;
        }
#pragma unroll
        for (int i = 0; i < 4; ++i) {
            const int r = i * 16 + jr;
            const int q = (js - (r >> 1)) & 3;
            gb[i] = (size_t)(n0 + r) * K + q * 8;
        }
        int aoff[2], boff[4];
#pragma unroll
        for (int mt = 0; mt < 2; ++mt) {
            const int r = mt * 16 + ln15;
            aoff[mt] = (r * 4 + ((quad + (r >> 1)) & 3)) * 16;
        }
#pragma unroll
        for (int nt = 0; nt < 4; ++nt) {
            const int r = nt * 16 + ln15;
            boff[nt] = (r * 4 + ((quad + (r >> 1)) & 3)) * 16;
        }

        f4 acc[2][4];
#pragma unroll
        for (int i = 0; i < 2; ++i)
#pragma unroll
            for (int j = 0; j < 4; ++j) acc[i][j] = (f4){0.f, 0.f, 0.f, 0.f};

        // preload k0 = 0
#pragma unroll
        for (int i = 0; i < 2; ++i) GLLS16(Ap + ga[i], Al + i * 512);
#pragma unroll
        for (int i = 0; i < 4; ++i) GLLS16(Bt + gb[i], Bl + i * 512);

        for (int k0 = 0; k0 < K; k0 += 32) {
            WAIT_VM0();             // current tile-chunk DMA landed
            h8 aF[2], bF[4];
#pragma unroll
            for (int nt = 0; nt < 4; ++nt)
                bF[nt] = *(const h8*)((const char*)Bl + boff[nt]);
#pragma unroll
            for (int mt = 0; mt < 2; ++mt)
                aF[mt] = *(const h8*)((const char*)Al + aoff[mt]);
            WAIT_LGKM0();           // frag reads retired before overwrite
            if (k0 + 32 < K) {      // prefetch next chunk behind the MFMAs
#pragma unroll
                for (int i = 0; i < 2; ++i)
                    GLLS16(Ap + ga[i] + k0 + 32, Al + i * 512);
#pragma unroll
                for (int i = 0; i < 4; ++i)
                    GLLS16(Bt + gb[i] + k0 + 32, Bl + i * 512);
            }
#pragma unroll
            for (int mt = 0; mt < 2; ++mt)
#pragma unroll
                for (int nt = 0; nt < 4; ++nt)
                    acc[mt][nt] = __builtin_amdgcn_mfma_f32_16x16x32_f16(
                        aF[mt], bF[nt], acc[mt][nt], 0, 0, 0);
        }

#pragma unroll
        for (int nt = 0; nt < 4; ++nt) {
            const int gn = n0 + nt * 16 + ln15;
            const float bs = bias[gn];
#pragma unroll
            for (int mt = 0; mt < 2; ++mt) {
#pragma unroll
                for (int r = 0; r < 4; ++r) {
                    const int gm = m0 + mt * 16 + quad * 4 + r;
                    float v = acc[mt][nt][r] + bs;
                    if (GELU) v = 0.5f * v * (1.0f + erff(v * 0.70710678118654752f));
                    if (RESID == 1) v += ((const float*)resid)[(size_t)gm * N + gn];
                    if (RESID == 2) v += (float)((const f16*)resid)[(size_t)gm * N + gn];
                    if (QKV) {
                        if (gn < 256) ((f16*)out1)[(size_t)gm * 256 + gn] = (f16)v;
                        else ((f16*)outkv)[(size_t)gm * 512 + (gn - 256)] = (f16)v;
                    } else if (OUTF32) {
                        ((float*)out1)[(size_t)gm * N + gn] = v;
                    } else {
                        ((f16*)out1)[(size_t)gm * N + gn] = (f16)v;
                    }
                }
            }
        }
    }
}

// ---------------- the cooperative mega-kernel ----------------
__global__ __launch_bounds__(512, 2) void mega_kernel(
    const float* __restrict__ x, const float* __restrict__ x_kv,
    const float* __restrict__ Wq, const float* __restrict__ Wk,
    const float* __restrict__ Wv, const float* __restrict__ Wp,
    const float* __restrict__ W1, const float* __restrict__ W2,
    const float* __restrict__ bq, const float* __restrict__ bk,
    const float* __restrict__ bv, const float* __restrict__ bp,
    const float* __restrict__ bm1, const float* __restrict__ bm2,
    const float* __restrict__ g1, const float* __restrict__ b1,
    const float* __restrict__ g2, const float* __restrict__ b2,
    f16* WqkvT, f16* WpT, f16* W1T, f16* W2T, float* bqkv,
    f16* hq, f16* hkv, f16* qf, f16* kvf, f16* ao, f16* x1, f16* m2,
    f16* hidF, float* outp)
{
    cg::grid_group grid = cg::this_grid();
    __shared__ __align__(16) char smem[49152];   // 8 wave-slots x 6 KB
    const int tid = threadIdx.x;
    const int wid = tid >> 6, lane = tid & 63;
    const int gw = blockIdx.x * 8 + wid;          // global wave 0..2047
    f16* slot = (f16*)smem + wid * 3072;

    // ---- phase A: weight transpose/cast (fp32 [K][N] -> f16 [N][K]) + LN1 ----
    {
        float (*tb)[33] = (float(*)[33])smem;
        const int rr = tid >> 5, cc = tid & 31;   // rr 0..15
#pragma unroll 1
        for (int i = 0; i < 3; ++i) {
            int bx = blockIdx.x * 3 + i;          // 0..767
            const float* src; f16* dst; int K, N;
            if (bx < 64)        { src = Wq; dst = WqkvT;           K = 256;  N = 256; }
            else if (bx < 128)  { src = Wk; dst = WqkvT + 65536;   K = 256;  N = 256;  bx -= 64; }
            else if (bx < 192)  { src = Wv; dst = WqkvT + 131072;  K = 256;  N = 256;  bx -= 128; }
            else if (bx < 256)  { src = Wp; dst = WpT;             K = 256;  N = 256;  bx -= 192; }
            else if (bx < 512)  { src = W1; dst = W1T;             K = 256;  N = 1024; bx -= 256; }
            else                { src = W2; dst = W2T;             K = 1024; N = 256;  bx -= 512; }
            const int tN = N >> 5;
            const int kt = bx / tN, nt = bx - kt * tN;
#pragma unroll
            for (int j = 0; j < 2; ++j)
                tb[rr + 16 * j][cc] =
                    src[(size_t)(kt * 32 + rr + 16 * j) * N + nt * 32 + cc];
            __syncthreads();
#pragma unroll
            for (int j = 0; j < 2; ++j)
                dst[(size_t)(nt * 32 + rr + 16 * j) * K + kt * 32 + cc] =
                    (f16)tb[cc][rr + 16 * j];
            __syncthreads();
        }
        if (blockIdx.x == 0 && tid < 256) {
            bqkv[tid]       = bq[tid];
            bqkv[tid + 256] = bk[tid];
            bqkv[tid + 512] = bv[tid];
        }
        // LN1: one wave per row, grid-stride over 2*BNROWS rows
        for (int r = gw; r < 2 * BNROWS; r += NWAVES) {
            const float* src; f16* dst;
            if (r < BNROWS) { src = x + (size_t)r * CC; dst = hq + (size_t)r * CC; }
            else { src = x_kv + (size_t)(r - BNROWS) * CC; dst = hkv + (size_t)(r - BNROWS) * CC; }
            const float4 v = ((const float4*)src)[lane];
            const float mu = wave_sum64(v.x + v.y + v.z + v.w) * (1.0f / CC);
            const float d0 = v.x - mu, d1 = v.y - mu, d2 = v.z - mu, d3 = v.w - mu;
            const float var = wave_sum64(d0 * d0 + d1 * d1 + d2 * d2 + d3 * d3) * (1.0f / CC);
            const float rs = rsqrtf(var + 1e-6f);
            const float4 g4 = ((const float4*)g1)[lane];
            const float4 b4 = ((const float4*)b1)[lane];
            h2 o01 = (h2){(f16)(d0 * rs * g4.x + b4.x), (f16)(d1 * rs * g4.y + b4.y)};
            h2 o23 = (h2){(f16)(d2 * rs * g4.z + b4.z), (f16)(d3 * rs * g4.w + b4.w)};
            ((h2*)dst)[lane * 2] = o01;
            ((h2*)dst)[lane * 2 + 1] = o23;
        }
    }
    __threadfence();
    grid.sync();

    // ---- phase B: fused Q|K|V projection (288 x 12 tiles) ----
    gemm_phase<false, 0, false, true>(slot, gw, hq, hkv, WqkvT, bqkv,
                                      nullptr, qf, kvf, 288, 12, 768, 256);
    __threadfence();
    grid.sync();

    // ---- phase C: sparse spatial attention, LDS-free ----
    // thread = (q, head); radius 3 -> <=29 neighbors; exp(-1e9-m)==0 in fp32
    // so only in-radius keys contribute (== reference softmax).
    {
        const int gthread = blockIdx.x * 512 + tid;
        if (gthread < BNROWS * 8) {
            const int h = gthread & 7, q = gthread >> 3;   // q: 0..9215
            const int b = q / NN, qi = q - b * NN;
            const int qy = qi / HS, qx = qi - qy * HS;
            const size_t rowb0 = (size_t)b * NN;
            const f16* qp = qf + (size_t)q * CC + h * 32;
            h8 qa0 = ((const h8*)qp)[0], qa1 = ((const h8*)qp)[1];
            h8 qa2 = ((const h8*)qp)[2], qa3 = ((const h8*)qp)[3];
            const h2* q2a = (const h2*)&qa0;
            const h2* q2b = (const h2*)&qa1;
            const h2* q2c = (const h2*)&qa2;
            const h2* q2d = (const h2*)&qa3;

            float s[29];
#pragma unroll
            for (int n = 0; n < 29; ++n) {
                const int ky = qy + ATT_DY[n], kx = qx + ATT_DX[n];
                float sn = -1e30f;
                if ((unsigned)ky < HS && (unsigned)kx < HS) {
                    const f16* kp = kvf + (rowb0 + ky * HS + kx) * 512 + h * 32;
                    h8 k0 = ((const h8*)kp)[0], k1 = ((const h8*)kp)[1];
                    h8 k2 = ((const h8*)kp)[2], k3 = ((const h8*)kp)[3];
                    const h2* k2a = (const h2*)&k0;
                    const h2* k2b = (const h2*)&k1;
                    const h2* k2c = (const h2*)&k2;
                    const h2* k2d = (const h2*)&k3;
                    float a0 = 0.f, a1 = 0.f, a2_ = 0.f, a3 = 0.f;
#pragma unroll
                    for (int i = 0; i < 4; ++i) {
                        a0 = __builtin_amdgcn_fdot2(q2a[i], k2a[i], a0, false);
                        a1 = __builtin_amdgcn_fdot2(q2b[i], k2b[i], a1, false);
                        a2_ = __builtin_amdgcn_fdot2(q2c[i], k2c[i], a2_, false);
                        a3 = __builtin_amdgcn_fdot2(q2d[i], k2d[i], a3, false);
                    }
                    sn = ((a0 + a1) + (a2_ + a3)) * ATTN_SCALE;
                }
                s[n] = sn;
            }
            float m = s[0];
#pragma unroll
            for (int n = 1; n < 29; ++n) m = fmaxf(m, s[n]);
            float l = 0.0f;
#pragma unroll
            for (int n = 0; n < 29; ++n) { s[n] = __expf(s[n] - m); l += s[n]; }

            h2 a2[16];
#pragma unroll
            for (int i = 0; i < 16; ++i) a2[i] = (h2){(f16)0.f, (f16)0.f};
#pragma unroll
            for (int n = 0; n < 29; ++n) {
                const int ky = qy + ATT_DY[n], kx = qx + ATT_DX[n];
                if ((unsigned)ky < HS && (unsigned)kx < HS) {
                    const f16* vp = kvf + (rowb0 + ky * HS + kx) * 512 + 256 + h * 32;
                    const h2* v2 = (const h2*)vp;
                    const f16 pn = (f16)s[n];
                    const h2 ph = (h2){pn, pn};
#pragma unroll
                    for (int i = 0; i < 16; ++i) a2[i] += ph * v2[i];
                }
            }
            const float inv = 1.0f / l;
            h8 ov[4];
            f16* oh = (f16*)ov;
#pragma unroll
            for (int i = 0; i < 16; ++i) {
                oh[2 * i]     = (f16)((float)a2[i][0] * inv);
                oh[2 * i + 1] = (f16)((float)a2[i][1] * inv);
            }
            h8* dst = (h8*)(ao + (size_t)q * CC + h * 32);
#pragma unroll
            for (int i = 0; i < 4; ++i) dst[i] = ov[i];
        }
    }
    __threadfence();
    grid.sync();

    // ---- phase D: out-projection + fp32 x residual -> x1 (f16) ----
    gemm_phase<false, 1, false, false>(slot, gw, ao, nullptr, WpT, bp,
                                       x, x1, nullptr, 288, 4, 256, 256);
    __threadfence();
    grid.sync();

    // ---- phase E: LN2 (x1 -> m2) ----
    for (int r = gw; r < BNROWS; r += NWAVES) {
        const f16* src = x1 + (size_t)r * CC;
        const h2 a01 = ((const h2*)src)[lane * 2];
        const h2 a23 = ((const h2*)src)[lane * 2 + 1];
        const float v0 = (float)a01[0], v1 = (float)a01[1];
        const float v2 = (float)a23[0], v3 = (float)a23[1];
        const float mu = wave_sum64(v0 + v1 + v2 + v3) * (1.0f / CC);
        const float d0 = v0 - mu, d1 = v1 - mu, d2 = v2 - mu, d3 = v3 - mu;
        const float var = wave_sum64(d0 * d0 + d1 * d1 + d2 * d2 + d3 * d3) * (1.0f / CC);
        const float rs = rsqrtf(var + 1e-6f);
        const float4 g4 = ((const float4*)g2)[lane];
        const float4 b4 = ((const float4*)b2)[lane];
        f16* dst = m2 + (size_t)r * CC;
        h2 o01 = (h2){(f16)(d0 * rs * g4.x + b4.x), (f16)(d1 * rs * g4.y + b4.y)};
        h2 o23 = (h2){(f16)(d2 * rs * g4.z + b4.z), (f16)(d3 * rs * g4.w + b4.w)};
        ((h2*)dst)[lane * 2] = o01;
        ((h2*)dst)[lane * 2 + 1] = o23;
    }
    __threadfence();
    grid.sync();

    // ---- phase F: MLP up + GELU (288 x 16 tiles) ----
    gemm_phase<true, 0, false, false>(slot, gw, m2, nullptr, W1T, bm1,
                                      nullptr, hidF, nullptr, 288, 16, 1024, 256);
    __threadfence();
    grid.sync();

    // ---- phase G: MLP down + f16 x1 residual -> fp32 d_out ----
    gemm_phase<false, 2, true, false>(slot, gw, hidF, nullptr, W2T, bm2,
                                      x1, outp, nullptr, 288, 4, 256, 1024);
}

extern "C" void kernel_launch(void* const* d_in, const int* in_sizes, int n_in,
                              void* d_out, int out_size, void* d_ws, size_t ws_size,
                              hipStream_t stream) {
    const float* x    = (const float*)d_in[0];
    const float* x_kv = (const float*)d_in[1];
    const float* Wq   = (const float*)d_in[2];
    const float* bq   = (const float*)d_in[3];
    const float* Wk   = (const float*)d_in[4];
    const float* bk   = (const float*)d_in[5];
    const float* Wv   = (const float*)d_in[6];
    const float* bv   = (const float*)d_in[7];
    const float* Wp   = (const float*)d_in[8];
    const float* bp   = (const float*)d_in[9];
    const float* g1   = (const float*)d_in[10];
    const float* b1   = (const float*)d_in[11];
    const float* g2   = (const float*)d_in[12];
    const float* b2   = (const float*)d_in[13];
    const float* W1   = (const float*)d_in[14];
    const float* bm1  = (const float*)d_in[15];
    const float* W2   = (const float*)d_in[16];
    const float* bm2  = (const float*)d_in[17];
    float* outp = (float*)d_out;   // fp32 output (verified)

    // ws carve, no overlays (~58 MB of 268 MB)
    f16* wsh = (f16*)d_ws;
    f16* WqkvT = wsh;                       // 196608
    f16* WpT   = wsh + 196608;              // 65536
    f16* W1T   = wsh + 262144;              // 262144
    f16* W2T   = wsh + 524288;              // 262144
    float* bqkv = (float*)(wsh + 786432);   // 768 fp32 (1536 f16)
    f16* hq    = wsh + 787968;
    f16* hkv   = hq  + 2359296;
    f16* qf    = hkv + 2359296;
    f16* kvf   = qf  + 2359296;             // 4718592
    f16* ao    = kvf + 4718592;
    f16* x1    = ao  + 2359296;
    f16* m2    = x1  + 2359296;
    f16* hidF  = m2  + 2359296;             // 9437184

    void* args[] = {
        (void*)&x, (void*)&x_kv,
        (void*)&Wq, (void*)&Wk, (void*)&Wv, (void*)&Wp, (void*)&W1, (void*)&W2,
        (void*)&bq, (void*)&bk, (void*)&bv, (void*)&bp, (void*)&bm1, (void*)&bm2,
        (void*)&g1, (void*)&b1, (void*)&g2, (void*)&b2,
        (void*)&WqkvT, (void*)&WpT, (void*)&W1T, (void*)&W2T, (void*)&bqkv,
        (void*)&hq, (void*)&hkv, (void*)&qf, (void*)&kvf, (void*)&ao,
        (void*)&x1, (void*)&m2, (void*)&hidF, (void*)&outp
    };
    hipLaunchCooperativeKernel(reinterpret_cast<void*>(mega_kernel),
                               dim3(256), dim3(512), args, 0, stream);
    (void)in_sizes; (void)n_in; (void)out_size; (void)ws_size;
}

// Round 12
// 195.875 us; speedup vs baseline: 3.6700x; 3.6700x over previous
//
#include <hip/hip_runtime.h>
#include <hip/hip_fp16.h>
#include <math.h>

#define BB 4
#define NN 2304
#define CC 256
#define HS 48
#define HID 1024
#define BNROWS (BB * NN)                 // 9216
#define ATTN_SCALE 0.17677669529663687f  // 32^-0.5

typedef _Float16 f16;
typedef __attribute__((ext_vector_type(2))) _Float16 h2;
typedef __attribute__((ext_vector_type(8))) _Float16 h8;
typedef __attribute__((ext_vector_type(4))) float f4;

#define GLLS16(g, l)                                                        \
    __builtin_amdgcn_global_load_lds(                                       \
        (const __attribute__((address_space(1))) unsigned int*)(g),         \
        (__attribute__((address_space(3))) unsigned int*)(l), 16, 0, 0)
// global_load_lds -> ds_read dependency is untracked by the compiler;
// explicit waits with memory clobber pin the ordering.
#define WAIT_VM0()   asm volatile("s_waitcnt vmcnt(0)" ::: "memory")
#define WAIT_VM6()   asm volatile("s_waitcnt vmcnt(6)" ::: "memory")
#define WAIT_LGKM0() asm volatile("s_waitcnt lgkmcnt(0)" ::: "memory")

static __device__ __forceinline__ float wave_sum64(float v) {
    v += __shfl_xor(v, 32, 64);
    v += __shfl_xor(v, 16, 64);
    v += __shfl_xor(v, 8, 64);
    v += __shfl_xor(v, 4, 64);
    v += __shfl_xor(v, 2, 64);
    v += __shfl_xor(v, 1, 64);
    return v;
}

// ---------------- merged prep + LN1 ----------------
// blocks 0..767:  32x32 transpose tiles, fp32 [K][N] -> f16 [N][K]
// block  768:     fused qkv bias
// blocks 769+:    LN1, one wave per row (4 rows/block), fp32 -> f16
__global__ __launch_bounds__(256) void prep_ln1_kernel(
    const float* __restrict__ x, const float* __restrict__ xkv,
    const float* __restrict__ Wq, const float* __restrict__ Wk,
    const float* __restrict__ Wv, const float* __restrict__ Wp,
    const float* __restrict__ W1, const float* __restrict__ W2,
    const float* __restrict__ bq, const float* __restrict__ bk,
    const float* __restrict__ bv,
    const float* __restrict__ g, const float* __restrict__ be,
    f16* __restrict__ WqkvT, f16* __restrict__ WpT,
    f16* __restrict__ W1T, f16* __restrict__ W2T, float* __restrict__ bqkv,
    f16* __restrict__ hq, f16* __restrict__ hkv)
{
    __shared__ float tt[32][33];
    int bx = blockIdx.x;
    const int tid = threadIdx.x;
    if (bx < 768) {
        const float* src; f16* dst; int K, N;
        if (bx < 64)        { src = Wq; dst = WqkvT;           K = 256;  N = 256; }
        else if (bx < 128)  { src = Wk; dst = WqkvT + 65536;   K = 256;  N = 256;  bx -= 64; }
        else if (bx < 192)  { src = Wv; dst = WqkvT + 131072;  K = 256;  N = 256;  bx -= 128; }
        else if (bx < 256)  { src = Wp; dst = WpT;             K = 256;  N = 256;  bx -= 192; }
        else if (bx < 512)  { src = W1; dst = W1T;             K = 256;  N = 1024; bx -= 256; }
        else                { src = W2; dst = W2T;             K = 1024; N = 256;  bx -= 512; }
        const int tN = N >> 5;
        const int kt = bx / tN, nt = bx - kt * tN;
        const int rr = tid >> 5, cc = tid & 31;
#pragma unroll
        for (int j = 0; j < 4; ++j)
            tt[rr + 8 * j][cc] = src[(size_t)(kt * 32 + rr + 8 * j) * N + nt * 32 + cc];
        __syncthreads();
#pragma unroll
        for (int j = 0; j < 4; ++j)
            dst[(size_t)(nt * 32 + rr + 8 * j) * K + kt * 32 + cc] = (f16)tt[cc][rr + 8 * j];
        return;
    }
    if (bx == 768) {
        if (tid < 256) {
            bqkv[tid]       = bq[tid];
            bqkv[tid + 256] = bk[tid];
            bqkv[tid + 512] = bv[tid];
        }
        return;
    }
    // LN1
    const int r = (bx - 769) * 4 + (tid >> 6);  // 0..2*BNROWS-1
    const int lane = tid & 63;
    const float* src; f16* dst;
    if (r < BNROWS) { src = x + (size_t)r * CC;              dst = hq + (size_t)r * CC; }
    else { src = xkv + (size_t)(r - BNROWS) * CC; dst = hkv + (size_t)(r - BNROWS) * CC; }
    const float4 v = ((const float4*)src)[lane];
    const float mu = wave_sum64(v.x + v.y + v.z + v.w) * (1.0f / CC);
    const float d0 = v.x - mu, d1 = v.y - mu, d2 = v.z - mu, d3 = v.w - mu;
    const float var = wave_sum64(d0 * d0 + d1 * d1 + d2 * d2 + d3 * d3) * (1.0f / CC);
    const float rs = rsqrtf(var + 1e-6f);
    const float4 g4 = ((const float4*)g)[lane];
    const float4 b4 = ((const float4*)be)[lane];
    h2 o01 = (h2){(f16)(d0 * rs * g4.x + b4.x), (f16)(d1 * rs * g4.y + b4.y)};
    h2 o23 = (h2){(f16)(d2 * rs * g4.z + b4.z), (f16)(d3 * rs * g4.w + b4.w)};
    ((h2*)dst)[lane * 2] = o01;
    ((h2*)dst)[lane * 2 + 1] = o23;
}

// ---------------- LN2 ----------------
__global__ __launch_bounds__(256) void ln2_kernel(
    const f16* __restrict__ x1, const float* __restrict__ g,
    const float* __restrict__ be, f16* __restrict__ m2)
{
    const int r = blockIdx.x * 4 + (threadIdx.x >> 6);
    const int lane = threadIdx.x & 63;
    const f16* src = x1 + (size_t)r * CC;
    const h2 a01 = ((const h2*)src)[lane * 2];
    const h2 a23 = ((const h2*)src)[lane * 2 + 1];
    const float v0 = (float)a01[0], v1 = (float)a01[1];
    const float v2 = (float)a23[0], v3 = (float)a23[1];
    const float mu = wave_sum64(v0 + v1 + v2 + v3) * (1.0f / CC);
    const float d0 = v0 - mu, d1 = v1 - mu, d2 = v2 - mu, d3 = v3 - mu;
    const float var = wave_sum64(d0 * d0 + d1 * d1 + d2 * d2 + d3 * d3) * (1.0f / CC);
    const float rs = rsqrtf(var + 1e-6f);
    const float4 g4 = ((const float4*)g)[lane];
    const float4 b4 = ((const float4*)be)[lane];
    f16* dst = m2 + (size_t)r * CC;
    h2 o01 = (h2){(f16)(d0 * rs * g4.x + b4.x), (f16)(d1 * rs * g4.y + b4.y)};
    h2 o23 = (h2){(f16)(d2 * rs * g4.z + b4.z), (f16)(d3 * rs * g4.w + b4.w)};
    ((h2*)dst)[lane * 2] = o01;
    ((h2*)dst)[lane * 2 + 1] = o23;
}

// ---------------- wave-autonomous MFMA GEMM, double-buffered ----------------
// Wave owns a 32(M)x64(N) tile. Two private 6 KB LDS buffers; while MFMA
// consumes buf[cur], the next K-chunk DMAs into buf[nxt]; s_waitcnt vmcnt(6)
// drains only the 6 oldest loads (= buf[cur]) -> ~latency/2 exposed in-wave.
// LDS chunk swizzle: (row r, k-chunk q) -> slot (q+(r>>1))&3 [2-way = free].
template <bool GELU, int RESID, bool OUTF32, bool QKV>
__global__ __launch_bounds__(256, 4) void gemm_wave(
    const f16* __restrict__ Aq, const f16* __restrict__ Akv,
    const f16* __restrict__ Bt, const float* __restrict__ bias,
    const void* __restrict__ resid, void* __restrict__ out1,
    void* __restrict__ outkv, int N, int K)
{
    __shared__ f16 lds[4 * 6144];   // 4 waves x 2 buffers x 3072 f16 = 48 KB
    const int tid = threadIdx.x;
    const int wid = tid >> 6, lane = tid & 63;
    const int ln15 = lane & 15, quad = lane >> 4;
    const int jr = lane >> 2, js = lane & 3;
    f16* slot = lds + wid * 6144;
    const int n0 = blockIdx.x * 64;
    const int m0 = (blockIdx.y * 4 + wid) * 32;
    const f16* Ap = QKV ? (n0 < 256 ? Aq : Akv) : Aq;

    // glls per-lane source offsets (element units, k0 added per iter)
    size_t ga[2], gb[4];
#pragma unroll
    for (int i = 0; i < 2; ++i) {
        const int r = i * 16 + jr;
        const int q = (js - (r >> 1)) & 3;
        ga[i] = (size_t)(m0 + r) * K + q * 8;
    }
#pragma unroll
    for (int i = 0; i < 4; ++i) {
        const int r = i * 16 + jr;
        const int q = (js - (r >> 1)) & 3;
        gb[i] = (size_t)(n0 + r) * K + q * 8;
    }
    // frag LDS byte offsets (swizzled), relative to buffer base
    int aoff[2], boff[4];
#pragma unroll
    for (int mt = 0; mt < 2; ++mt) {
        const int r = mt * 16 + ln15;
        aoff[mt] = (r * 4 + ((quad + (r >> 1)) & 3)) * 16;
    }
#pragma unroll
    for (int nt = 0; nt < 4; ++nt) {
        const int r = nt * 16 + ln15;
        boff[nt] = (r * 4 + ((quad + (r >> 1)) & 3)) * 16;
    }

    f4 acc[2][4];
#pragma unroll
    for (int i = 0; i < 2; ++i)
#pragma unroll
        for (int j = 0; j < 4; ++j) acc[i][j] = (f4){0.f, 0.f, 0.f, 0.f};

    // preload chunk 0 into buffer 0
    {
        f16* Al = slot;
        f16* Bl = slot + 1024;
#pragma unroll
        for (int i = 0; i < 2; ++i) GLLS16(Ap + ga[i], Al + i * 512);
#pragma unroll
        for (int i = 0; i < 4; ++i) GLLS16(Bt + gb[i], Bl + i * 512);
    }

    int cur = 0;
    for (int k0 = 0; k0 < K; k0 += 32) {
        const bool more = (k0 + 32 < K);
        f16* Ac = slot + cur * 3072;
        f16* Bc = Ac + 1024;
        if (more) {
            f16* An = slot + (cur ^ 1) * 3072;
            f16* Bn = An + 1024;
            WAIT_LGKM0();   // prior frag reads of that buffer retired (cheap)
#pragma unroll
            for (int i = 0; i < 2; ++i) GLLS16(Ap + ga[i] + k0 + 32, An + i * 512);
#pragma unroll
            for (int i = 0; i < 4; ++i) GLLS16(Bt + gb[i] + k0 + 32, Bn + i * 512);
            WAIT_VM6();     // only the 6 oldest (= buf[cur]) must have landed
        } else {
            WAIT_VM0();
        }
        h8 aF[2], bF[4];
#pragma unroll
        for (int nt = 0; nt < 4; ++nt)
            bF[nt] = *(const h8*)((const char*)Bc + boff[nt]);
#pragma unroll
        for (int mt = 0; mt < 2; ++mt)
            aF[mt] = *(const h8*)((const char*)Ac + aoff[mt]);
#pragma unroll
        for (int mt = 0; mt < 2; ++mt)
#pragma unroll
            for (int nt = 0; nt < 4; ++nt)
                acc[mt][nt] = __builtin_amdgcn_mfma_f32_16x16x32_f16(
                    aF[mt], bF[nt], acc[mt][nt], 0, 0, 0);
        cur ^= 1;
    }

#pragma unroll
    for (int nt = 0; nt < 4; ++nt) {
        const int gn = n0 + nt * 16 + ln15;
        const float bs = bias[gn];
#pragma unroll
        for (int mt = 0; mt < 2; ++mt) {
#pragma unroll
            for (int r = 0; r < 4; ++r) {
                const int gm = m0 + mt * 16 + quad * 4 + r;
                float v = acc[mt][nt][r] + bs;
                if (GELU) v = 0.5f * v * (1.0f + erff(v * 0.70710678118654752f));
                if (RESID == 1) v += ((const float*)resid)[(size_t)gm * N + gn];
                if (RESID == 2) v += (float)((const f16*)resid)[(size_t)gm * N + gn];
                if (QKV) {
                    if (gn < 256) ((f16*)out1)[(size_t)gm * 256 + gn] = (f16)v;
                    else ((f16*)outkv)[(size_t)gm * 512 + (gn - 256)] = (f16)v;
                } else if (OUTF32) {
                    ((float*)out1)[(size_t)gm * N + gn] = v;
                } else {
                    ((f16*)out1)[(size_t)gm * N + gn] = (f16)v;
                }
            }
        }
    }
}

// ---------------- tiled sparse spatial attention (r10-proven) ----------------
// exp(-1e9-m)==0 in fp32 so only in-radius keys contribute (== reference).
__device__ __constant__ int ATT_DY[29] = {
    -3, -2, -2, -2, -2, -2, -1, -1, -1, -1, -1, 0, 0, 0, 0,
    0, 0, 0, 1, 1, 1, 1, 1, 2, 2, 2, 2, 2, 3};
__device__ __constant__ int ATT_DX[29] = {
    0, -2, -1, 0, 1, 2, -2, -1, 0, 1, 2, -3, -2, -1, 0,
    1, 2, 3, -2, -1, 0, 1, 2, -2, -1, 0, 1, 2, 0};

__global__ __launch_bounds__(128) void attn_tile_kernel(
    const f16* __restrict__ qf, const f16* __restrict__ kvf,
    f16* __restrict__ ao)
{
    __shared__ f16 ks[196][66];
    __shared__ f16 vs[196][66];
    const int tile = blockIdx.x, hp = blockIdx.y, b = blockIdx.z;
    const int ty0 = (tile / 6) * 8, tx0 = (tile - (tile / 6) * 6) * 8;
    const int tid = threadIdx.x;

    for (int idx = tid; idx < 196 * 16; idx += 128) {
        const int r = idx >> 4, seg = idx & 15;
        const int gy = ty0 - 3 + r / 14, gx = tx0 - 3 + (r - (r / 14) * 14);
        uint4 val = {0u, 0u, 0u, 0u};
        if ((unsigned)gy < HS && (unsigned)gx < HS) {
            const size_t rowb = ((size_t)b * NN + gy * HS + gx) * 512;
            const int ch = (seg < 8) ? (hp * 64 + seg * 8)
                                     : (256 + hp * 64 + (seg - 8) * 8);
            val = *(const uint4*)&kvf[rowb + ch];
        }
        f16* dstp = (seg < 8) ? &ks[r][(seg & 7) * 8] : &vs[r][(seg & 7) * 8];
        ((unsigned int*)dstp)[0] = val.x;
        ((unsigned int*)dstp)[1] = val.y;
        ((unsigned int*)dstp)[2] = val.z;
        ((unsigned int*)dstp)[3] = val.w;
    }
    __syncthreads();

    const int q = tid & 63, hh = tid >> 6;
    const int qy = q >> 3, qx = q & 7;
    const size_t qrow = (size_t)b * NN + (ty0 + qy) * HS + tx0 + qx;
    const f16* qp = qf + qrow * CC + hp * 64 + hh * 32;
    uint4 qa[4];
#pragma unroll
    for (int i = 0; i < 4; ++i) qa[i] = ((const uint4*)qp)[i];
    const h2* q2 = (const h2*)qa;

    float s[29];
#pragma unroll
    for (int n = 0; n < 29; ++n) {
        const int dy = ATT_DY[n], dx = ATT_DX[n];
        const int r = (qy + 3 + dy) * 14 + qx + 3 + dx;
        const bool valid = (unsigned)(ty0 + qy + dy) < HS &&
                           (unsigned)(tx0 + qx + dx) < HS;
        float a = 0.0f;
        const h2* kp = (const h2*)&ks[r][hh * 32];
#pragma unroll
        for (int i = 0; i < 16; ++i)
            a = __builtin_amdgcn_fdot2(q2[i], kp[i], a, false);
        s[n] = valid ? a * ATTN_SCALE : -1e30f;
    }
    float m = s[0];
#pragma unroll
    for (int n = 1; n < 29; ++n) m = fmaxf(m, s[n]);
    float l = 0.0f;
#pragma unroll
    for (int n = 0; n < 29; ++n) { s[n] = __expf(s[n] - m); l += s[n]; }
    h2 a2[16];
#pragma unroll
    for (int i = 0; i < 16; ++i) a2[i] = (h2){(f16)0.f, (f16)0.f};
#pragma unroll
    for (int n = 0; n < 29; ++n) {
        const int dy = ATT_DY[n], dx = ATT_DX[n];
        const int r = (qy + 3 + dy) * 14 + qx + 3 + dx;
        const f16 pn = (f16)s[n];
        const h2 ph = (h2){pn, pn};
        const h2* vp = (const h2*)&vs[r][hh * 32];
#pragma unroll
        for (int i = 0; i < 16; ++i) a2[i] += ph * vp[i];
    }
    const float inv = 1.0f / l;
    uint4 ov[4];
    f16* oh = (f16*)ov;
#pragma unroll
    for (int i = 0; i < 16; ++i) {
        oh[2 * i]     = (f16)((float)a2[i][0] * inv);
        oh[2 * i + 1] = (f16)((float)a2[i][1] * inv);
    }
    uint4* dst = (uint4*)(ao + qrow * CC + hp * 64 + hh * 32);
#pragma unroll
    for (int i = 0; i < 4; ++i) dst[i] = ov[i];
}

extern "C" void kernel_launch(void* const* d_in, const int* in_sizes, int n_in,
                              void* d_out, int out_size, void* d_ws, size_t ws_size,
                              hipStream_t stream) {
    const float* x    = (const float*)d_in[0];
    const float* x_kv = (const float*)d_in[1];
    const float* Wq   = (const float*)d_in[2];
    const float* bq   = (const float*)d_in[3];
    const float* Wk   = (const float*)d_in[4];
    const float* bk   = (const float*)d_in[5];
    const float* Wv   = (const float*)d_in[6];
    const float* bv   = (const float*)d_in[7];
    const float* Wp   = (const float*)d_in[8];
    const float* bp   = (const float*)d_in[9];
    const float* g1   = (const float*)d_in[10];
    const float* b1   = (const float*)d_in[11];
    const float* g2   = (const float*)d_in[12];
    const float* b2   = (const float*)d_in[13];
    const float* W1   = (const float*)d_in[14];
    const float* bm1  = (const float*)d_in[15];
    const float* W2   = (const float*)d_in[16];
    const float* bm2  = (const float*)d_in[17];
    float* outp = (float*)d_out;   // fp32 output (verified)

    // ws layout (f16 element offsets); overlays by stream-ordered lifetime:
    //   ao over hq (dead after qkv); x1 over hkv (dead after qkv);
    //   m2 over qf (dead after attn); hidF over kvf.. (dead after attn).
    f16* wsh = (f16*)d_ws;
    f16* WqkvT = wsh;                      // 196608
    f16* WpT   = wsh + 196608;             // 65536
    f16* W1T   = wsh + 262144;             // 262144
    f16* W2T   = wsh + 524288;             // 262144
    float* bqkv = (float*)(wsh + 786432);  // 768 fp32
    f16* hq    = wsh + 787968;             // 2359296
    f16* hkv   = wsh + 3147264;            // 2359296
    f16* qf    = wsh + 5506560;            // 2359296
    f16* kvf   = wsh + 7865856;            // 4718592 (end 12584448)
    f16* ao    = hq;
    f16* x1    = hkv;
    f16* m2    = qf;
    f16* hidF  = kvf;                      // 9437184 -> end 17303040 (34.6 MB)
    const bool fused = ws_size >= (size_t)17303040 * sizeof(f16);

    // 1. merged weight prep + LN1 (769 + 4608 blocks)
    prep_ln1_kernel<<<5377, 256, 0, stream>>>(
        x, x_kv, Wq, Wk, Wv, Wp, W1, W2, bq, bk, bv, g1, b1,
        WqkvT, WpT, W1T, W2T, bqkv, hq, hkv);
    // 2. fused Q|K|V projection: tiles 288(M) x 12(N), 4 waves/block
    gemm_wave<false, 0, false, true><<<dim3(12, 72), 256, 0, stream>>>(
        hq, hkv, WqkvT, bqkv, nullptr, qf, kvf, 768, 256);
    // 3. attention
    attn_tile_kernel<<<dim3(36, 4, BB), 128, 0, stream>>>(qf, kvf, ao);
    // 4. out-proj + fp32 x residual -> x1 (f16)
    gemm_wave<false, 1, false, false><<<dim3(4, 72), 256, 0, stream>>>(
        ao, nullptr, WpT, bp, x, x1, nullptr, 256, 256);
    // 5. LN2 -> m2
    ln2_kernel<<<BNROWS / 4, 256, 0, stream>>>(x1, g2, b2, m2);
    // 6/7. MLP
    if (fused) {
        gemm_wave<true, 0, false, false><<<dim3(16, 72), 256, 0, stream>>>(
            m2, nullptr, W1T, bm1, nullptr, hidF, nullptr, 1024, 256);
        gemm_wave<false, 2, true, false><<<dim3(4, 72), 256, 0, stream>>>(
            hidF, nullptr, W2T, bm2, x1, outp, nullptr, 256, 1024);
    } else {
        for (int b = 0; b < BB; ++b) {
            const size_t off = (size_t)b * NN * CC;
            gemm_wave<true, 0, false, false><<<dim3(16, 18), 256, 0, stream>>>(
                m2 + off, nullptr, W1T, bm1, nullptr, hidF, nullptr, 1024, 256);
            gemm_wave<false, 2, true, false><<<dim3(4, 18), 256, 0, stream>>>(
                hidF, nullptr, W2T, bm2, x1 + off, outp + off, nullptr, 256, 1024);
        }
    }
    (void)in_sizes; (void)n_in; (void)out_size;
}